// Round 3
// baseline (984.982 us; speedup 1.0000x reference)
//
#include <hip/hip_runtime.h>
#include <hip/hip_bf16.h>

#define BATCH 4
#define CCH 256
#define TLEN 8192
#define LAYERS 10
#define BCT (BATCH*CCH*TLEN)   // 8,388,608 elements
#define TPAD 1024              // causal zero-pad rows per batch (max shift = 2*512)
#define TROWS (TPAD + TLEN)    // 9216

typedef __attribute__((ext_vector_type(8))) short bf16x8;
typedef __attribute__((ext_vector_type(4))) float f32x4;
typedef __attribute__((ext_vector_type(4))) unsigned short u16x4;

__device__ __forceinline__ unsigned short f2b(float f) {
  union { float f; unsigned u; } v; v.f = f;
  unsigned r = (v.u + 0x7FFFu + ((v.u >> 16) & 1u)) >> 16;
  return (unsigned short)r;
}
__device__ __forceinline__ float b2f(unsigned short h) {
  union { unsigned u; float f; } v; v.u = ((unsigned)h) << 16;
  return v.f;
}

// async global->LDS, 16 B per lane; lds base must be wave-uniform,
// lane i's data lands at lds + i*16 (m104/m108 semantics).
__device__ __forceinline__ void gload16(const void* g, void* l) {
  __builtin_amdgcn_global_load_lds((__attribute__((address_space(1))) void*)g,
                                   (__attribute__((address_space(3))) void*)l, 16, 0, 0);
}

__device__ __forceinline__ float fast_tanh(float x) {
  float a = fabsf(x);
  float e = __expf(-2.f * a);                       // in (0,1]
  float th = (1.f - e) * __builtin_amdgcn_rcpf(1.f + e);
  return copysignf(th, x);
}
__device__ __forceinline__ float fast_sigmoid(float x) {
  return __builtin_amdgcn_rcpf(1.f + __expf(-x));
}

// ---------------------------------------------------------------------------
// Weight repack:
//  wconv [L][512][256][3] fp32 -> Wb [L][3][2 yblk][256 row][256 c] bf16,
//    rows pre-interleaved into the conv kernel's gate-pairing order:
//    ch(y,row) = y*128 + ((row>>5)<<4) + (row&15) + (((row>>4)&1)<<8)
//  wout [L][256][256] fp32 -> Wob same layout bf16
// ---------------------------------------------------------------------------
__global__ void repack_w(const float* __restrict__ wc, const float* __restrict__ wo,
                         unsigned short* __restrict__ Wb, unsigned short* __restrict__ Wob) {
  size_t g = (size_t)blockIdx.x * 256 + threadIdx.x;
  const size_t NA = (size_t)LAYERS * 3 * 2 * 256 * 256;
  if (g < NA) {
    int c   = (int)(g & 255);
    int row = (int)((g >> 8) & 255);
    int y   = (int)((g >> 16) & 1);
    int lt  = (int)(g >> 17);           // l*3 + tap
    int tap = lt % 3, l = lt / 3;
    int ch = y * 128 + ((row >> 5) << 4) + (row & 15) + (((row >> 4) & 1) << 8);
    Wb[g] = f2b(wc[(((size_t)l * 512 + ch) * 256 + c) * 3 + tap]);
  } else {
    size_t g2 = g - NA;
    if (g2 < (size_t)LAYERS * 256 * 256) Wob[g2] = f2b(wo[g2]);
  }
}

// ---------------------------------------------------------------------------
// Zero the causal pad rows of xTb (workspace is poisoned to 0xAA each call).
// ---------------------------------------------------------------------------
__global__ void zero_pads(unsigned short* __restrict__ xTb) {
  size_t off = (size_t)blockIdx.y * TROWS * CCH;
  int i = blockIdx.x * 256 + threadIdx.x;     // 128*256 = 32768 threads * 16 B = 512 KB
  ulonglong2 z; z.x = 0ull; z.y = 0ull;
  ((ulonglong2*)(xTb + off))[i] = z;
}

// ---------------------------------------------------------------------------
// Transpose input [B][C][T] fp32 -> xT [B][T][C] fp32 AND xTb bf16 (padded).
// 64x64 tile, float4 transactions both directions (G13), LDS [64][65].
// ---------------------------------------------------------------------------
__global__ __launch_bounds__(256)
void transpose_in(const float* __restrict__ in, float* __restrict__ xT,
                  unsigned short* __restrict__ xTb) {
  __shared__ float tile[64][65];                 // [c-local][t-local]
  const int tid = threadIdx.x;
  const int t0 = blockIdx.x * 64, c0 = blockIdx.y * 64, b = blockIdx.z;
  const int q4 = (tid & 15) * 4, r0 = tid >> 4;
#pragma unroll
  for (int p = 0; p < 4; ++p) {
    const int r = r0 + 16 * p;                   // c-local
    float4 v = *(const float4*)&in[((size_t)b * CCH + c0 + r) * TLEN + t0 + q4];
    tile[r][q4 + 0] = v.x; tile[r][q4 + 1] = v.y;
    tile[r][q4 + 2] = v.z; tile[r][q4 + 3] = v.w;
  }
  __syncthreads();
#pragma unroll
  for (int p = 0; p < 4; ++p) {
    const int tr = r0 + 16 * p;                  // t-local
    float4 v;
    v.x = tile[q4 + 0][tr]; v.y = tile[q4 + 1][tr];
    v.z = tile[q4 + 2][tr]; v.w = tile[q4 + 3][tr];
    *(float4*)&xT[((size_t)b * TLEN + t0 + tr) * CCH + c0 + q4] = v;
    u16x4 h; h.x = f2b(v.x); h.y = f2b(v.y); h.z = f2b(v.z); h.w = f2b(v.w);
    *(u16x4*)&xTb[((size_t)b * TROWS + TPAD + t0 + tr) * CCH + c0 + q4] = h;
  }
}

// ---------------------------------------------------------------------------
// Final: out[B][C][T] = xT[B][T][C] + hT(bf16)[B][T][C], float4 both ways.
// ---------------------------------------------------------------------------
__global__ __launch_bounds__(256)
void final_addT(const float* __restrict__ xT, const unsigned short* __restrict__ hT,
                float* __restrict__ out) {
  __shared__ float tile[64][65];                 // [t-local][c-local]
  const int tid = threadIdx.x;
  const int t0 = blockIdx.x * 64, c0 = blockIdx.y * 64, b = blockIdx.z;
  const int q4 = (tid & 15) * 4, r0 = tid >> 4;
#pragma unroll
  for (int p = 0; p < 4; ++p) {
    const int tr = r0 + 16 * p;                  // t-local
    size_t idx = ((size_t)b * TLEN + t0 + tr) * CCH + c0 + q4;
    float4 x = *(const float4*)&xT[idx];
    u16x4 h = *(const u16x4*)&hT[idx];
    tile[tr][q4 + 0] = x.x + b2f(h.x);
    tile[tr][q4 + 1] = x.y + b2f(h.y);
    tile[tr][q4 + 2] = x.z + b2f(h.z);
    tile[tr][q4 + 3] = x.w + b2f(h.w);
  }
  __syncthreads();
#pragma unroll
  for (int p = 0; p < 4; ++p) {
    const int c = r0 + 16 * p;                   // c-local
    float4 v;
    v.x = tile[q4 + 0][c]; v.y = tile[q4 + 1][c];
    v.z = tile[q4 + 2][c]; v.w = tile[q4 + 3][c];
    *(float4*)&out[((size_t)b * CCH + c0 + c) * TLEN + t0 + q4] = v;
  }
}

// ---------------------------------------------------------------------------
// Dilated causal conv + gate — 256x256 tile, counted-vmcnt schedule.
// (UNCHANGED from round 2 — A/B attribution.)
// ---------------------------------------------------------------------------
__global__ __launch_bounds__(512, 2)
void conv_gate_kernel(const unsigned short* __restrict__ xTb, // [B][TROWS][C] bf16
                      const unsigned short* __restrict__ Wl,  // [3][2][256][256] bf16, this layer
                      const float* __restrict__ bias,         // [512] fp32
                      unsigned short* __restrict__ hT,        // [B][T][C] bf16
                      float* __restrict__ skip,               // [B][C][T] fp32, this layer
                      int d) {
  __shared__ __align__(16) unsigned short As[3][256 * 32];  // 48 KiB, [slot][row][32 k]
  __shared__ __align__(16) unsigned short Bs[3][256 * 32];  // 48 KiB

  const int tid  = threadIdx.x;          // 0..511
  const int lane = tid & 63;
  const int wv   = tid >> 6;             // 0..7
  const int wm   = wv & 1;               // time half (128 rows each)
  const int wn   = wv >> 1;              // 0..3: 64-weight-row quarter
  const int col  = lane & 15, quad = lane >> 4;

  const int bid  = blockIdx.x;
  const int swzb = (bid & 7) * 32 + (bid >> 3);
  const int t0   = (swzb & 31) * 256;
  const int y    = (swzb >> 5) & 1;
  const int b    = swzb >> 6;

  const int srow  = lane >> 2;           // staging row within 16-row chunk
  const int sslot = lane & 3;            // staging 16B slot within 64B row

  const unsigned short* Arow = xTb + ((size_t)b * TROWS + TPAD + t0) * CCH;

  f32x4 acc[8][4];
  const f32x4 zero = {0.f, 0.f, 0.f, 0.f};
#pragma unroll
  for (int i = 0; i < 8; ++i)
#pragma unroll
    for (int j = 0; j < 4; ++j) acc[i][j] = zero;

  auto stageA = [&](int kt, int slot) {
    const int tap = kt >> 3, c0 = (kt & 7) << 5;
    const unsigned short* Ab = Arow - (size_t)((2 - tap) * d) * CCH + c0;
#pragma unroll
    for (int j = 0; j < 2; ++j) {
      const int row = (wv * 2 + j) * 16 + srow;
      const int ss  = sslot ^ ((row >> 1) & 3);
      gload16(Ab + (size_t)row * CCH + ss * 8, &As[slot][(wv * 2 + j) * 512]);
    }
  };
  auto stageB = [&](int kt, int slot) {
    const int tap = kt >> 3, c0 = (kt & 7) << 5;
    const unsigned short* Wp = Wl + ((size_t)(tap * 2 + y)) * (256 * 256) + c0;
#pragma unroll
    for (int j = 0; j < 2; ++j) {
      const int row = (wv * 2 + j) * 16 + srow;
      const int ss  = sslot ^ ((row >> 1) & 3);
      gload16(Wp + (size_t)row * 256 + ss * 8, &Bs[slot][(wv * 2 + j) * 512]);
    }
  };

  auto ktile = [&](int slot, int stageKt, bool vm4) {
    if (vm4) asm volatile("s_waitcnt vmcnt(4)" ::: "memory");
    else     asm volatile("s_waitcnt vmcnt(0)" ::: "memory");
    __builtin_amdgcn_s_barrier();
    const int pslot = (slot + 2) % 3;
    bf16x8 bf[4], af[4];
#pragma unroll
    for (int nf = 0; nf < 4; ++nf) {
      const int row = wn * 64 + nf * 16 + col;
      bf[nf] = *(const bf16x8*)&Bs[slot][row * 32 + ((quad ^ ((row >> 1) & 3)) << 3)];
    }
#pragma unroll
    for (int mf = 0; mf < 4; ++mf) {
      const int row = wm * 128 + mf * 16 + col;
      af[mf] = *(const bf16x8*)&As[slot][row * 32 + ((quad ^ ((row >> 1) & 3)) << 3)];
    }
    if (stageKt >= 0) stageA(stageKt, pslot);
    __builtin_amdgcn_s_setprio(1);
#pragma unroll
    for (int mf = 0; mf < 4; ++mf)
#pragma unroll
      for (int nf = 0; nf < 4; ++nf)
        acc[mf][nf] = __builtin_amdgcn_mfma_f32_16x16x32_bf16(af[mf], bf[nf], acc[mf][nf], 0, 0, 0);
    __builtin_amdgcn_s_setprio(0);
    __builtin_amdgcn_sched_barrier(0);
#pragma unroll
    for (int mf = 0; mf < 4; ++mf) {
      const int row = wm * 128 + (mf + 4) * 16 + col;
      af[mf] = *(const bf16x8*)&As[slot][row * 32 + ((quad ^ ((row >> 1) & 3)) << 3)];
    }
    if (stageKt >= 0) stageB(stageKt, pslot);
    __builtin_amdgcn_s_setprio(1);
#pragma unroll
    for (int mf = 0; mf < 4; ++mf)
#pragma unroll
      for (int nf = 0; nf < 4; ++nf)
        acc[mf + 4][nf] = __builtin_amdgcn_mfma_f32_16x16x32_bf16(af[mf], bf[nf], acc[mf + 4][nf], 0, 0, 0);
    __builtin_amdgcn_s_setprio(0);
    asm volatile("s_waitcnt lgkmcnt(0)" ::: "memory");
    __builtin_amdgcn_sched_barrier(0);
  };

  stageA(0, 0); stageB(0, 0);
  stageA(1, 1); stageB(1, 1);

#pragma unroll 1
  for (int kt = 0; kt < 21; kt += 3) {
    ktile(0, kt + 2, true);
    ktile(1, kt + 3, true);
    ktile(2, kt + 4, true);
  }
  ktile(0, 23, true);
  ktile(1, -1, true);
  ktile(2, -1, false);

#pragma unroll
  for (int p = 0; p < 2; ++p) {
    const int chn = y * 128 + (wn * 2 + p) * 16 + col;
    const float btop = bias[chn];
    const float bbot = bias[chn + 256];
    const size_t skipBase = ((size_t)b * CCH + chn) * TLEN;
#pragma unroll
    for (int mf = 0; mf < 8; ++mf) {
      const int tb = t0 + wm * 128 + mf * 16 + quad * 4;
      f32x4 zt = acc[mf][2 * p];
      f32x4 zb = acc[mf][2 * p + 1];
      float hr[4];
#pragma unroll
      for (int r = 0; r < 4; ++r) {
        float h = fast_tanh(zt[r] + btop) * fast_sigmoid(zb[r] + bbot);
        hr[r] = h;
        hT[((size_t)b * TLEN + tb + r) * CCH + chn] = f2b(h);
      }
      float4 hv; hv.x = hr[0]; hv.y = hr[1]; hv.z = hr[2]; hv.w = hr[3];
      *(float4*)&skip[skipBase + tb] = hv;
    }
  }
}

// ---------------------------------------------------------------------------
// 1x1 transform + residual — ported to the 3-slot counted-vmcnt schedule
// proven on conv_gate (R2): vmcnt(4) not 0 until tail, 1 barrier/K-tile,
// T2 row-XOR swizzle (both sides), setprio around the MFMA cluster.
//   xT[b][t][o] += sum_c Wo[o][c] * h[b][t][c] + bout[o]
// ---------------------------------------------------------------------------
__global__ __launch_bounds__(256, 2)
void onexone_kernel(const unsigned short* __restrict__ hT,  // [B][T][C] bf16
                    const unsigned short* __restrict__ Wo,  // [256][256] bf16, this layer
                    const float* __restrict__ bias,         // [256]
                    float* __restrict__ xT,                 // [B][T][C] fp32, in-place
                    unsigned short* __restrict__ xTb) {     // [B][TROWS][C] bf16
  __shared__ __align__(16) unsigned short As[3][128 * 32];  // 24 KiB
  __shared__ __align__(16) unsigned short Bs[3][128 * 32];  // 24 KiB

  const int tid  = threadIdx.x;        // 0..255
  const int lane = tid & 63;
  const int wv   = tid >> 6;           // 0..3
  const int wm   = wv & 1, wn = wv >> 1;
  const int col  = lane & 15, quad = lane >> 4;

  const int t0 = blockIdx.x * 128;
  const int o0 = blockIdx.y * 128;
  const int b  = blockIdx.z;

  const int srow  = lane >> 2;
  const int sslot = lane & 3;

  const unsigned short* Ab = hT + ((size_t)b * TLEN + t0) * CCH;
  const unsigned short* Wb = Wo + (size_t)o0 * 256;

  f32x4 acc[4][4];
  const f32x4 zero = {0.f, 0.f, 0.f, 0.f};
#pragma unroll
  for (int i = 0; i < 4; ++i)
#pragma unroll
    for (int j = 0; j < 4; ++j) acc[i][j] = zero;

  // stage one K-tile (BK=32): A (h rows) + B (weight rows), 4 gload16/thread.
  auto stage = [&](int kt, int slot) {
    const int c0 = kt << 5;
#pragma unroll
    for (int j = 0; j < 2; ++j) {
      const int row = (wv * 2 + j) * 16 + srow;
      const int ss  = sslot ^ ((row >> 1) & 3);
      gload16(Ab + (size_t)row * CCH + c0 + ss * 8, &As[slot][(wv * 2 + j) * 512]);
    }
#pragma unroll
    for (int j = 0; j < 2; ++j) {
      const int row = (wv * 2 + j) * 16 + srow;
      const int ss  = sslot ^ ((row >> 1) & 3);
      gload16(Wb + (size_t)row * 256 + c0 + ss * 8, &Bs[slot][(wv * 2 + j) * 512]);
    }
  };

  auto ktile = [&](int slot, int stageKt, bool vm4) {
    if (vm4) asm volatile("s_waitcnt vmcnt(4)" ::: "memory");
    else     asm volatile("s_waitcnt vmcnt(0)" ::: "memory");
    __builtin_amdgcn_s_barrier();
    bf16x8 af[4], bf[4];
#pragma unroll
    for (int nf = 0; nf < 4; ++nf) {
      const int row = wn * 64 + nf * 16 + col;
      bf[nf] = *(const bf16x8*)&Bs[slot][row * 32 + ((quad ^ ((row >> 1) & 3)) << 3)];
    }
#pragma unroll
    for (int mf = 0; mf < 4; ++mf) {
      const int row = wm * 64 + mf * 16 + col;
      af[mf] = *(const bf16x8*)&As[slot][row * 32 + ((quad ^ ((row >> 1) & 3)) << 3)];
    }
    if (stageKt >= 0) stage(stageKt, (slot + 2) % 3);
    __builtin_amdgcn_s_setprio(1);
#pragma unroll
    for (int mf = 0; mf < 4; ++mf)
#pragma unroll
      for (int nf = 0; nf < 4; ++nf)
        acc[mf][nf] = __builtin_amdgcn_mfma_f32_16x16x32_bf16(af[mf], bf[nf], acc[mf][nf], 0, 0, 0);
    __builtin_amdgcn_s_setprio(0);
    // all my ds_reads of this slot returned before crossing the next barrier
    asm volatile("s_waitcnt lgkmcnt(0)" ::: "memory");
    __builtin_amdgcn_sched_barrier(0);
  };

  stage(0, 0); stage(1, 1);
  ktile(0, 2, true);
  ktile(1, 3, true);
  ktile(2, 4, true);
  ktile(0, 5, true);
  ktile(1, 6, true);
  ktile(2, 7, true);
  ktile(0, -1, true);    // kt=6: outstanding = kt6's 4 + kt7's 4 -> wait to 4
  ktile(1, -1, false);   // kt=7: drain

#pragma unroll
  for (int mf = 0; mf < 4; ++mf) {
    const int tb = t0 + wm * 64 + mf * 16 + quad * 4;
#pragma unroll
    for (int nf = 0; nf < 4; ++nf) {
      const int ch = o0 + wn * 64 + nf * 16 + col;
      const float bo = bias[ch];
#pragma unroll
      for (int r = 0; r < 4; ++r) {
        size_t idx = ((size_t)b * TLEN + tb + r) * CCH + ch;
        float nv = xT[idx] + acc[mf][nf][r] + bo;
        xT[idx] = nv;
        xTb[((size_t)b * TROWS + TPAD + tb + r) * CCH + ch] = f2b(nv);
      }
    }
  }
}

// ---------------------------------------------------------------------------
extern "C" void kernel_launch(void* const* d_in, const int* in_sizes, int n_in,
                              void* d_out, int out_size, void* d_ws, size_t ws_size,
                              hipStream_t stream) {
  const float* input = (const float*)d_in[0];
  const float* wconv = (const float*)d_in[1];
  const float* bconv = (const float*)d_in[2];
  const float* wout  = (const float*)d_in[3];
  const float* bout  = (const float*)d_in[4];
  float* out   = (float*)d_out;
  float* skips = out + (size_t)BCT;        // [L][B][C][T]

  char* ws = (char*)d_ws;
  float*          xT  = (float*)ws;                                    // BCT fp32
  unsigned short* xTb = (unsigned short*)(ws + (size_t)BCT * 4);       // B*TROWS*C bf16
  unsigned short* hT  = (unsigned short*)(ws + (size_t)BCT * 4
                                             + (size_t)BATCH * TROWS * CCH * 2);
  unsigned short* Wb  = hT + (size_t)BCT;                              // L*3*2*256*256
  unsigned short* Wob = Wb + (size_t)LAYERS * 3 * 512 * 256;           // L*256*256

  static const int dil[LAYERS] = {1, 2, 4, 8, 16, 32, 64, 128, 256, 512};

  repack_w<<<17920, 256, 0, stream>>>(wconv, wout, Wb, Wob);
  zero_pads<<<dim3(128, BATCH), 256, 0, stream>>>(xTb);
  transpose_in<<<dim3(TLEN / 64, CCH / 64, BATCH), 256, 0, stream>>>(input, xT, xTb);

  for (int l = 0; l < LAYERS; ++l) {
    conv_gate_kernel<<<256, 512, 0, stream>>>(
        xTb, Wb + (size_t)l * 3 * 512 * 256, bconv + (size_t)l * 512,
        hT, skips + (size_t)l * BCT, dil[l]);
    if (l < LAYERS - 1) {
      onexone_kernel<<<dim3(TLEN / 128, 2, BATCH), 256, 0, stream>>>(
          hT, Wob + (size_t)l * 256 * 256, bout + (size_t)l * 256, xT, xTb);
    } else {
      final_addT<<<dim3(TLEN / 64, CCH / 64, BATCH), 256, 0, stream>>>(xT, hT, out);
    }
  }
}